// Round 4
// baseline (890.622 us; speedup 1.0000x reference)
//
#include <hip/hip_runtime.h>
#include <hip/hip_bf16.h>

#define N_NODES 50000
#define N_EDGES 400000
#define E_TOT   450000   // + self loops
#define N_GRAPHS 256
#define F_IN 128
#define HID 64
#define SCAN_NB 196      // ceil(50000/256)

// ---------------- degree / dinv ----------------
__global__ void k_deg(const int* __restrict__ dstp, int* __restrict__ degi) {
    int e = blockIdx.x * blockDim.x + threadIdx.x;
    if (e < N_EDGES) atomicAdd(&degi[dstp[e]], 1);
}

__global__ void k_dinv(const int* __restrict__ degi, float* __restrict__ dinv) {
    int i = blockIdx.x * blockDim.x + threadIdx.x;
    if (i < N_NODES) dinv[i] = rsqrtf(1.0f + (float)degi[i]);  // self-loop => deg>=1
}

// ---------------- CSR build: exclusive scan of (deg+1) ----------------
__global__ void k_scan1(const int* __restrict__ degi, int* __restrict__ rowptr,
                        int* __restrict__ partial) {
    __shared__ int s[256];
    int i = blockIdx.x * 256 + threadIdx.x;
    int v = (i < N_NODES) ? (degi[i] + 1) : 0;
    s[threadIdx.x] = v;
    __syncthreads();
    for (int off = 1; off < 256; off <<= 1) {
        int t = (threadIdx.x >= off) ? s[threadIdx.x - off] : 0;
        __syncthreads();
        s[threadIdx.x] += t;
        __syncthreads();
    }
    if (i < N_NODES) rowptr[i] = s[threadIdx.x] - v;
    if (threadIdx.x == 255) partial[blockIdx.x] = s[255];
}

__global__ void k_scan2(int* __restrict__ partial) {
    __shared__ int s[256];
    int v = (threadIdx.x < SCAN_NB) ? partial[threadIdx.x] : 0;
    s[threadIdx.x] = v;
    __syncthreads();
    for (int off = 1; off < 256; off <<= 1) {
        int t = (threadIdx.x >= off) ? s[threadIdx.x - off] : 0;
        __syncthreads();
        s[threadIdx.x] += t;
        __syncthreads();
    }
    if (threadIdx.x < SCAN_NB) partial[threadIdx.x] = s[threadIdx.x] - v;
}

__global__ void k_scan3(int* __restrict__ rowptr, const int* __restrict__ partial) {
    int i = blockIdx.x * 256 + threadIdx.x;
    if (i < N_NODES) rowptr[i] += partial[blockIdx.x];
    if (i == 0) rowptr[N_NODES] = E_TOT;
}

__global__ void k_fill_self(const int* __restrict__ rowptr, const float* __restrict__ dinv,
                            int* __restrict__ csr_src, float* __restrict__ csr_norm,
                            int* __restrict__ cursor) {
    int i = blockIdx.x * blockDim.x + threadIdx.x;
    if (i >= N_NODES) return;
    int p = rowptr[i];
    csr_src[p] = i;
    float di = dinv[i];
    csr_norm[p] = di * di;
    cursor[i] = 1;
}

__global__ void k_fill_edge(const int* __restrict__ srcp, const int* __restrict__ dstp,
                            const int* __restrict__ rowptr, const float* __restrict__ dinv,
                            int* __restrict__ cursor, int* __restrict__ csr_src,
                            float* __restrict__ csr_norm) {
    int e = blockIdx.x * blockDim.x + threadIdx.x;
    if (e >= N_EDGES) return;
    int s = srcp[e], d = dstp[e];
    int p = rowptr[d] + atomicAdd(&cursor[d], 1);
    csr_src[p] = s;
    csr_norm[p] = dinv[s] * dinv[d];
}

// ---------------- tiled GEMM: out[N,64] = x[N,K] @ w[K,64]  (+bias, relu if EPI) ----------
// block = 256 thr: 64 rows x 64 cols, per-thread 4x4 register block, W K-tiled in LDS.
template <int K, bool EPI>
__global__ void k_gemm_v3(const float* __restrict__ x, const float* __restrict__ w,
                          const float* __restrict__ bias, float* __restrict__ out,
                          int nrows) {
    __shared__ float sw[64 * 64];
    const int tid = threadIdx.x;
    const int wave = tid >> 6, lane = tid & 63;
    const int g = lane >> 4, l16 = lane & 15;
    const int c0 = l16 * 4;
    const int r0 = blockIdx.x * 64 + wave * 16 + g * 4;
    int ri[4];
#pragma unroll
    for (int i = 0; i < 4; ++i) ri[i] = min(r0 + i, nrows - 1);  // clamp, store is guarded
    float4 acc[4];
#pragma unroll
    for (int i = 0; i < 4; ++i) acc[i] = make_float4(0.f, 0.f, 0.f, 0.f);
    const float4* __restrict__ x4 = (const float4*)x;
    constexpr int KV = K / 4;
    for (int kt = 0; kt < K / 64; ++kt) {
        __syncthreads();
        for (int i = tid; i < 64 * 64; i += 256) {
            int k = i >> 6, j = i & 63;
            sw[i] = w[(kt * 64 + k) * 64 + j];
        }
        __syncthreads();
#pragma unroll
        for (int k4 = 0; k4 < 16; ++k4) {
            float4 xv[4];
#pragma unroll
            for (int i = 0; i < 4; ++i) xv[i] = x4[(size_t)ri[i] * KV + kt * 16 + k4];
            const float* swp = &sw[(k4 * 4) * 64 + c0];
#pragma unroll
            for (int kk = 0; kk < 4; ++kk) {
                float4 wv = *(const float4*)(swp + kk * 64);
#pragma unroll
                for (int i = 0; i < 4; ++i) {
                    float xs = (kk == 0) ? xv[i].x : (kk == 1) ? xv[i].y
                             : (kk == 2) ? xv[i].z : xv[i].w;
                    acc[i].x = fmaf(xs, wv.x, acc[i].x);
                    acc[i].y = fmaf(xs, wv.y, acc[i].y);
                    acc[i].z = fmaf(xs, wv.z, acc[i].z);
                    acc[i].w = fmaf(xs, wv.w, acc[i].w);
                }
            }
        }
    }
    float4 bv = make_float4(0.f, 0.f, 0.f, 0.f);
    if (EPI) bv = *(const float4*)(bias + c0);
#pragma unroll
    for (int i = 0; i < 4; ++i) {
        int r = r0 + i;
        if (r < nrows) {
            float4 v = acc[i];
            if (EPI) {
                v.x = fmaxf(v.x + bv.x, 0.f);
                v.y = fmaxf(v.y + bv.y, 0.f);
                v.z = fmaxf(v.z + bv.z, 0.f);
                v.w = fmaxf(v.w + bv.w, 0.f);
            }
            *(float4*)(out + (size_t)r * 64 + c0) = v;
        }
    }
}

// ---------------- GCN aggregate: wave/node, float4 lanes, 4 edges per pass ----------------
__global__ void k_gcn_gather4(const int* __restrict__ rowptr, const int* __restrict__ csr_src,
                              const float* __restrict__ csr_norm, const float* __restrict__ t,
                              const float* __restrict__ b, float* __restrict__ out) {
    int node = (blockIdx.x * blockDim.x + threadIdx.x) >> 6;
    int lane = threadIdx.x & 63;
    if (node >= N_NODES) return;
    int sub = lane >> 4, l16 = lane & 15;
    int beg = rowptr[node], end = rowptr[node + 1];
    const float4* __restrict__ t4 = (const float4*)t;
    float4 acc = {0.f, 0.f, 0.f, 0.f};
    for (int p0 = beg; p0 < end; p0 += 4) {
        int p = p0 + sub;
        if (p < end) {
            int s = csr_src[p];
            float nm = csr_norm[p];
            float4 v = t4[(size_t)s * 16 + l16];
            acc.x = fmaf(nm, v.x, acc.x);
            acc.y = fmaf(nm, v.y, acc.y);
            acc.z = fmaf(nm, v.z, acc.z);
            acc.w = fmaf(nm, v.w, acc.w);
        }
    }
#pragma unroll
    for (int m = 16; m <= 32; m <<= 1) {
        acc.x += __shfl_xor(acc.x, m);
        acc.y += __shfl_xor(acc.y, m);
        acc.z += __shfl_xor(acc.z, m);
        acc.w += __shfl_xor(acc.w, m);
    }
    if (lane < 16) {
        float4 bv = ((const float4*)b)[l16];
        float4 r;
        r.x = fmaxf(acc.x + bv.x, 0.f);
        r.y = fmaxf(acc.y + bv.y, 0.f);
        r.z = fmaxf(acc.z + bv.z, 0.f);
        r.w = fmaxf(acc.w + bv.w, 0.f);
        ((float4*)out)[(size_t)node * 16 + l16] = r;
    }
}

// ---------------- GAT ----------------
// wat[q*64 + cin] = sum_c gat_w[cin, h*64+c] * att[h][c],  q = h*2 + (0:src,1:dst)
__global__ void k_wat(const float* __restrict__ gat_w, const float* __restrict__ att_src,
                      const float* __restrict__ att_dst, float* __restrict__ wat) {
    int t = threadIdx.x;  // 512 threads
    int q = t >> 6, cin = t & 63;
    int h = q >> 1;
    const float* av = (q & 1) ? att_dst : att_src;
    float acc = 0.f;
#pragma unroll
    for (int c = 0; c < 64; ++c)
        acc = fmaf(gat_w[cin * 256 + h * 64 + c], av[h * 64 + c], acc);
    wat[t] = acc;
}

// wbig[(h*64+cin)*64 + c] = 0.25 * gat_w[cin*256 + h*64 + c]
__global__ void k_wbig(const float* __restrict__ gat_w, float* __restrict__ wbig) {
    int i = blockIdx.x * 256 + threadIdx.x;
    if (i >= 256 * 64) return;
    int k = i >> 6, c = i & 63;
    int h = k >> 6, cin = k & 63;
    wbig[i] = 0.25f * gat_w[cin * 256 + h * 64 + c];
}

// asrc/adst = bufA @ wat^T : wave per node
__global__ void k_att2(const float* __restrict__ xin, const float* __restrict__ wat,
                       float* __restrict__ asrc, float* __restrict__ adst) {
    __shared__ float sw[512];
    for (int i = threadIdx.x; i < 512; i += 256) sw[i] = wat[i];
    __syncthreads();
    int node = (blockIdx.x * blockDim.x + threadIdx.x) >> 6;
    int lane = threadIdx.x & 63;
    if (node >= N_NODES) return;
    float val = xin[(size_t)node * 64 + lane];
#pragma unroll
    for (int q = 0; q < 8; ++q) {
        float p = val * sw[q * 64 + lane];
#pragma unroll
        for (int m = 1; m <= 32; m <<= 1) p += __shfl_xor(p, m);
        if (lane == q) {
            if (q & 1) adst[node * 4 + (q >> 1)] = p;
            else       asrc[node * 4 + (q >> 1)] = p;
        }
    }
}

static __device__ __forceinline__ float lrelu02(float v) {
    return v >= 0.f ? v : 0.2f * v;
}

// per (edge,head) unnormalized exp + per (node,head) denominator
__global__ void k_gat_alpha(const int* __restrict__ rowptr, const int* __restrict__ csr_src,
                            const float* __restrict__ asrc, const float* __restrict__ adst,
                            float* __restrict__ ebuf, float* __restrict__ denom) {
    int node = (blockIdx.x * blockDim.x + threadIdx.x) >> 6;
    int lane = threadIdx.x & 63;
    if (node >= N_NODES) return;
    int h = lane & 3, esub = lane >> 2;  // 16 edges x 4 heads per pass
    int beg = rowptr[node], end = rowptr[node + 1];
    float ad = adst[node * 4 + h];
    float m = -1e30f;
    for (int base = beg; base < end; base += 16) {
        int e = base + esub;
        if (e < end) {
            int s = csr_src[e];
            m = fmaxf(m, lrelu02(asrc[s * 4 + h] + ad));
        }
    }
#pragma unroll
    for (int mk = 4; mk <= 32; mk <<= 1) m = fmaxf(m, __shfl_xor(m, mk));
    float den = 0.f;
    for (int base = beg; base < end; base += 16) {
        int e = base + esub;
        if (e < end) {
            int s = csr_src[e];
            float ex = expf(lrelu02(asrc[s * 4 + h] + ad) - m);
            den += ex;
            ebuf[e * 4 + h] = ex;  // == base*4 + lane : coalesced
        }
    }
#pragma unroll
    for (int mk = 4; mk <= 32; mk <<= 1) den += __shfl_xor(den, mk);
    if (lane < 4) denom[node * 4 + lane] = den;
}

// per-head normalized weighted sum of bufA rows: Pcat[node, h*64+c] (lane: h=lane>>4)
__global__ void k_gat_wsum(const int* __restrict__ rowptr, const int* __restrict__ csr_src,
                           const float* __restrict__ ebuf, const float* __restrict__ denom,
                           const float* __restrict__ bufA, float* __restrict__ pcat) {
    int node = (blockIdx.x * blockDim.x + threadIdx.x) >> 6;
    int lane = threadIdx.x & 63;
    if (node >= N_NODES) return;
    int h = lane >> 4, l16 = lane & 15;
    int beg = rowptr[node], end = rowptr[node + 1];
    const float4* __restrict__ a4 = (const float4*)bufA;
    float4 acc = {0.f, 0.f, 0.f, 0.f};
    for (int p = beg; p < end; ++p) {
        int s = csr_src[p];
        float a = ebuf[p * 4 + h];
        float4 v = a4[(size_t)s * 16 + l16];  // broadcast across the 4 head groups
        acc.x = fmaf(a, v.x, acc.x);
        acc.y = fmaf(a, v.y, acc.y);
        acc.z = fmaf(a, v.z, acc.z);
        acc.w = fmaf(a, v.w, acc.w);
    }
    float inv = 1.0f / denom[node * 4 + h];
    acc.x *= inv; acc.y *= inv; acc.z *= inv; acc.w *= inv;
    ((float4*)pcat)[(size_t)node * 64 + lane] = acc;  // = node*256 + h*64 + l16*4
}

// ---------------- pool (batch sorted: run-length accumulate, 32 nodes/wave) ----------------
__global__ void k_pool2(const int* __restrict__ batch, const float* __restrict__ h,
                        float* __restrict__ psum, float* __restrict__ pcnt) {
    int wave = (blockIdx.x * blockDim.x + threadIdx.x) >> 6;
    int lane = threadIdx.x & 63;
    int n0 = wave * 32;
    if (n0 >= N_NODES) return;
    int nend = min(n0 + 32, N_NODES);
    int cur = batch[n0];
    float acc = 0.f, cnt = 0.f;
    for (int n = n0; n < nend; ++n) {
        int g = batch[n];
        if (g != cur) {
            atomicAdd(&psum[cur * 64 + lane], acc);
            if (lane == 0) atomicAdd(&pcnt[cur], cnt);
            acc = 0.f; cnt = 0.f; cur = g;
        }
        acc += h[(size_t)n * 64 + lane];
        cnt += 1.f;
    }
    atomicAdd(&psum[cur * 64 + lane], acc);
    if (lane == 0) atomicAdd(&pcnt[cur], cnt);
}

__global__ void k_cls(const float* __restrict__ psum, const float* __restrict__ pcnt,
                      const float* __restrict__ cw1, const float* __restrict__ cb1,
                      const float* __restrict__ cw2, const float* __restrict__ cb2,
                      float* __restrict__ out) {
    int g = blockIdx.x;
    int j = threadIdx.x;
    __shared__ float sp[64];
    float rc = 1.0f / fmaxf(pcnt[g], 1.0f);
    sp[j] = psum[g * 64 + j] * rc;
    __syncthreads();
    float z = 0.f;
    if (j < 32) {
        float acc = 0.f;
#pragma unroll
        for (int k = 0; k < 64; ++k) acc = fmaf(sp[k], cw1[k * 32 + j], acc);
        acc += cb1[j];
        acc = fmaxf(acc, 0.f);
        z = acc * cw2[j];
    }
#pragma unroll
    for (int off = 32; off; off >>= 1) z += __shfl_down(z, off);
    if (j == 0) out[g] = z + cb2[0];
}

extern "C" void kernel_launch(void* const* d_in, const int* in_sizes, int n_in,
                              void* d_out, int out_size, void* d_ws, size_t ws_size,
                              hipStream_t stream) {
    const float* x       = (const float*)d_in[0];
    const int*   ei      = (const int*)d_in[1];
    const int*   batch   = (const int*)d_in[2];
    const float* w1      = (const float*)d_in[3];
    const float* b1      = (const float*)d_in[4];
    const float* w2      = (const float*)d_in[5];
    const float* b2      = (const float*)d_in[6];
    const float* w3      = (const float*)d_in[7];
    const float* b3      = (const float*)d_in[8];
    const float* gat_w   = (const float*)d_in[9];
    const float* att_src = (const float*)d_in[10];
    const float* att_dst = (const float*)d_in[11];
    const float* gat_b   = (const float*)d_in[12];
    const float* cw1     = (const float*)d_in[13];
    const float* cb1     = (const float*)d_in[14];
    const float* cw2     = (const float*)d_in[15];
    const float* cb2     = (const float*)d_in[16];
    float* out = (float*)d_out;

    const int* srcp = ei;
    const int* dstp = ei + N_EDGES;

    float* W = (float*)d_ws;
    size_t off = 0;
    float*    dinv    = W + off; off += N_NODES;
    int*      degi    = (int*)(W + off); off += N_NODES;
    int*      rowptr  = (int*)(W + off); off += N_NODES + 1;
    int*      partial = (int*)(W + off); off += 256;
    int*      cursor  = (int*)(W + off); off += N_NODES;
    int*      csr_src = (int*)(W + off); off += E_TOT;
    float*    csr_nrm = W + off; off += E_TOT;
    float*    bufT    = W + off; off += (size_t)N_NODES * HID;
    float*    bufA    = W + off; off += (size_t)N_NODES * HID;
    float*    bufB    = W + off; off += (size_t)N_NODES * HID;
    float*    pcat    = W + off; off += (size_t)N_NODES * 256;
    float*    asrc    = W + off; off += (size_t)N_NODES * 4;
    float*    adst    = W + off; off += (size_t)N_NODES * 4;
    float*    ebuf    = W + off; off += (size_t)E_TOT * 4;
    float*    denom   = W + off; off += (size_t)N_NODES * 4;
    float*    wat     = W + off; off += 512;
    float*    wbig    = W + off; off += 256 * 64;
    float*    psum    = W + off; off += (size_t)N_GRAPHS * HID;
    float*    pcnt    = W + off; off += N_GRAPHS;

    auto cdiv = [](int a, int b) { return (a + b - 1) / b; };

    hipMemsetAsync(degi, 0, N_NODES * sizeof(int), stream);
    hipMemsetAsync(psum, 0, (N_GRAPHS * HID + N_GRAPHS) * sizeof(float), stream);

    // degree / dinv / CSR
    k_deg<<<cdiv(N_EDGES, 256), 256, 0, stream>>>(dstp, degi);
    k_dinv<<<cdiv(N_NODES, 256), 256, 0, stream>>>(degi, dinv);
    k_scan1<<<SCAN_NB, 256, 0, stream>>>(degi, rowptr, partial);
    k_scan2<<<1, 256, 0, stream>>>(partial);
    k_scan3<<<SCAN_NB, 256, 0, stream>>>(rowptr, partial);
    k_fill_self<<<cdiv(N_NODES, 256), 256, 0, stream>>>(rowptr, dinv, csr_src, csr_nrm, cursor);
    k_fill_edge<<<cdiv(N_EDGES, 256), 256, 0, stream>>>(srcp, dstp, rowptr, dinv, cursor,
                                                        csr_src, csr_nrm);

    const int nWV = cdiv(N_NODES * 64, 256);   // wave-per-node kernels
    const int nGB = cdiv(N_NODES, 64);         // gemm blocks

    // GCN layer 1 (K=128): x -> bufA
    k_gemm_v3<F_IN, false><<<nGB, 256, 0, stream>>>(x, w1, nullptr, bufT, N_NODES);
    k_gcn_gather4<<<nWV, 256, 0, stream>>>(rowptr, csr_src, csr_nrm, bufT, b1, bufA);

    // GCN layer 2: bufA -> bufB
    k_gemm_v3<HID, false><<<nGB, 256, 0, stream>>>(bufA, w2, nullptr, bufT, N_NODES);
    k_gcn_gather4<<<nWV, 256, 0, stream>>>(rowptr, csr_src, csr_nrm, bufT, b2, bufB);

    // GCN layer 3: bufB -> bufA
    k_gemm_v3<HID, false><<<nGB, 256, 0, stream>>>(bufB, w3, nullptr, bufT, N_NODES);
    k_gcn_gather4<<<nWV, 256, 0, stream>>>(rowptr, csr_src, csr_nrm, bufT, b3, bufA);

    // GAT (no hg materialization: aggregate bufA per head, then one [N,256]@[256,64] GEMM)
    k_wat<<<1, 512, 0, stream>>>(gat_w, att_src, att_dst, wat);
    k_wbig<<<64, 256, 0, stream>>>(gat_w, wbig);
    k_att2<<<nWV, 256, 0, stream>>>(bufA, wat, asrc, adst);
    k_gat_alpha<<<nWV, 256, 0, stream>>>(rowptr, csr_src, asrc, adst, ebuf, denom);
    k_gat_wsum<<<nWV, 256, 0, stream>>>(rowptr, csr_src, ebuf, denom, bufA, pcat);
    k_gemm_v3<256, true><<<nGB, 256, 0, stream>>>(pcat, wbig, gat_b, bufB, N_NODES);

    // pool + classifier
    k_pool2<<<cdiv(cdiv(N_NODES, 32) * 64, 256), 256, 0, stream>>>(batch, bufB, psum, pcnt);
    k_cls<<<N_GRAPHS, 64, 0, stream>>>(psum, pcnt, cw1, cb1, cw2, cb2, out);
}

// Round 5
// 459.844 us; speedup vs baseline: 1.9368x; 1.9368x over previous
//
#include <hip/hip_runtime.h>
#include <hip/hip_bf16.h>

#define N_NODES 50000
#define N_EDGES 400000
#define E_TOT   450000   // + self loops
#define N_GRAPHS 256
#define F_IN 128
#define HID 64
#define SCAN_NB 196      // ceil(50000/256)

// ---------------- degree / dinv ----------------
__global__ void k_deg(const int* __restrict__ dstp, int* __restrict__ degi) {
    int e = blockIdx.x * blockDim.x + threadIdx.x;
    if (e < N_EDGES) atomicAdd(&degi[dstp[e]], 1);
}

__global__ void k_dinv(const int* __restrict__ degi, float* __restrict__ dinv) {
    int i = blockIdx.x * blockDim.x + threadIdx.x;
    if (i < N_NODES) dinv[i] = rsqrtf(1.0f + (float)degi[i]);  // self-loop => deg>=1
}

// ---------------- CSR build: exclusive scan of (deg+1) ----------------
__global__ void k_scan1(const int* __restrict__ degi, int* __restrict__ rowptr,
                        int* __restrict__ partial) {
    __shared__ int s[256];
    int i = blockIdx.x * 256 + threadIdx.x;
    int v = (i < N_NODES) ? (degi[i] + 1) : 0;
    s[threadIdx.x] = v;
    __syncthreads();
    for (int off = 1; off < 256; off <<= 1) {
        int t = (threadIdx.x >= off) ? s[threadIdx.x - off] : 0;
        __syncthreads();
        s[threadIdx.x] += t;
        __syncthreads();
    }
    if (i < N_NODES) rowptr[i] = s[threadIdx.x] - v;
    if (threadIdx.x == 255) partial[blockIdx.x] = s[255];
}

__global__ void k_scan2(int* __restrict__ partial) {
    __shared__ int s[256];
    int v = (threadIdx.x < SCAN_NB) ? partial[threadIdx.x] : 0;
    s[threadIdx.x] = v;
    __syncthreads();
    for (int off = 1; off < 256; off <<= 1) {
        int t = (threadIdx.x >= off) ? s[threadIdx.x - off] : 0;
        __syncthreads();
        s[threadIdx.x] += t;
        __syncthreads();
    }
    if (threadIdx.x < SCAN_NB) partial[threadIdx.x] = s[threadIdx.x] - v;
}

__global__ void k_scan3(int* __restrict__ rowptr, const int* __restrict__ partial) {
    int i = blockIdx.x * 256 + threadIdx.x;
    if (i < N_NODES) rowptr[i] += partial[blockIdx.x];
    if (i == 0) rowptr[N_NODES] = E_TOT;
}

__global__ void k_fill_self(const int* __restrict__ rowptr, const float* __restrict__ dinv,
                            int* __restrict__ csr_src, float* __restrict__ csr_norm,
                            int* __restrict__ cursor) {
    int i = blockIdx.x * blockDim.x + threadIdx.x;
    if (i >= N_NODES) return;
    int p = rowptr[i];
    csr_src[p] = i;
    float di = dinv[i];
    csr_norm[p] = di * di;
    cursor[i] = 1;
}

__global__ void k_fill_edge(const int* __restrict__ srcp, const int* __restrict__ dstp,
                            const int* __restrict__ rowptr, const float* __restrict__ dinv,
                            int* __restrict__ cursor, int* __restrict__ csr_src,
                            float* __restrict__ csr_norm) {
    int e = blockIdx.x * blockDim.x + threadIdx.x;
    if (e >= N_EDGES) return;
    int s = srcp[e], d = dstp[e];
    int p = rowptr[d] + atomicAdd(&cursor[d], 1);
    csr_src[p] = s;
    csr_norm[p] = dinv[s] * dinv[d];
}

// ---------------- tiled GEMM: out[N,64] = x[N,K] @ w[K,64]  (+bias, relu if EPI) ----------
// block = 256 thr: 64 rows x 64 cols, 4x4 register block per thread.
// ALL per-thread state in NAMED variables (no local arrays -> no scratch; rule #20).
#define FMA4(A, S, W)               \
    A.x = fmaf(S, W.x, A.x);        \
    A.y = fmaf(S, W.y, A.y);        \
    A.z = fmaf(S, W.z, A.z);        \
    A.w = fmaf(S, W.w, A.w);

template <int K, bool EPI>
__global__ __launch_bounds__(256) void k_gemm_v3(
        const float* __restrict__ x, const float* __restrict__ w,
        const float* __restrict__ bias, float* __restrict__ out, int nrows) {
    __shared__ float sw[64 * 64];
    const int tid = threadIdx.x;
    const int wave = tid >> 6, lane = tid & 63;
    const int g = lane >> 4, l16 = lane & 15;
    const int c0 = l16 * 4;
    const int r0 = blockIdx.x * 64 + wave * 16 + g * 4;
    constexpr int KV = K / 4;
    const int last = nrows - 1;
    const float4* __restrict__ x4 = (const float4*)x;
    const float4* __restrict__ p0 = x4 + (size_t)min(r0 + 0, last) * KV;
    const float4* __restrict__ p1 = x4 + (size_t)min(r0 + 1, last) * KV;
    const float4* __restrict__ p2 = x4 + (size_t)min(r0 + 2, last) * KV;
    const float4* __restrict__ p3 = x4 + (size_t)min(r0 + 3, last) * KV;
    float4 a0 = make_float4(0.f, 0.f, 0.f, 0.f);
    float4 a1 = a0, a2 = a0, a3 = a0;

    for (int kt = 0; kt < K / 64; ++kt) {
        __syncthreads();
        for (int i = tid; i < 64 * 64; i += 256) {
            int k = i >> 6, j = i & 63;
            sw[i] = w[(kt * 64 + k) * 64 + j];
        }
        __syncthreads();
        const int kb = kt * 16;
#pragma unroll 4
        for (int k4 = 0; k4 < 16; ++k4) {
            float4 xv0 = p0[kb + k4];
            float4 xv1 = p1[kb + k4];
            float4 xv2 = p2[kb + k4];
            float4 xv3 = p3[kb + k4];
            const float* swp = &sw[(k4 * 4) * 64 + c0];
            float4 wv0 = *(const float4*)(swp);
            float4 wv1 = *(const float4*)(swp + 64);
            float4 wv2 = *(const float4*)(swp + 128);
            float4 wv3 = *(const float4*)(swp + 192);
            FMA4(a0, xv0.x, wv0) FMA4(a1, xv1.x, wv0) FMA4(a2, xv2.x, wv0) FMA4(a3, xv3.x, wv0)
            FMA4(a0, xv0.y, wv1) FMA4(a1, xv1.y, wv1) FMA4(a2, xv2.y, wv1) FMA4(a3, xv3.y, wv1)
            FMA4(a0, xv0.z, wv2) FMA4(a1, xv1.z, wv2) FMA4(a2, xv2.z, wv2) FMA4(a3, xv3.z, wv2)
            FMA4(a0, xv0.w, wv3) FMA4(a1, xv1.w, wv3) FMA4(a2, xv2.w, wv3) FMA4(a3, xv3.w, wv3)
        }
    }
    float4 bv = make_float4(0.f, 0.f, 0.f, 0.f);
    if (EPI) bv = *(const float4*)(bias + c0);
    if (EPI) {
        a0.x = fmaxf(a0.x + bv.x, 0.f); a0.y = fmaxf(a0.y + bv.y, 0.f);
        a0.z = fmaxf(a0.z + bv.z, 0.f); a0.w = fmaxf(a0.w + bv.w, 0.f);
        a1.x = fmaxf(a1.x + bv.x, 0.f); a1.y = fmaxf(a1.y + bv.y, 0.f);
        a1.z = fmaxf(a1.z + bv.z, 0.f); a1.w = fmaxf(a1.w + bv.w, 0.f);
        a2.x = fmaxf(a2.x + bv.x, 0.f); a2.y = fmaxf(a2.y + bv.y, 0.f);
        a2.z = fmaxf(a2.z + bv.z, 0.f); a2.w = fmaxf(a2.w + bv.w, 0.f);
        a3.x = fmaxf(a3.x + bv.x, 0.f); a3.y = fmaxf(a3.y + bv.y, 0.f);
        a3.z = fmaxf(a3.z + bv.z, 0.f); a3.w = fmaxf(a3.w + bv.w, 0.f);
    }
    if (r0 + 0 < nrows) *(float4*)(out + (size_t)(r0 + 0) * 64 + c0) = a0;
    if (r0 + 1 < nrows) *(float4*)(out + (size_t)(r0 + 1) * 64 + c0) = a1;
    if (r0 + 2 < nrows) *(float4*)(out + (size_t)(r0 + 2) * 64 + c0) = a2;
    if (r0 + 3 < nrows) *(float4*)(out + (size_t)(r0 + 3) * 64 + c0) = a3;
}

// ---------------- GCN aggregate: wave/node, float4 lanes, 4 edges per pass ----------------
__global__ void k_gcn_gather4(const int* __restrict__ rowptr, const int* __restrict__ csr_src,
                              const float* __restrict__ csr_norm, const float* __restrict__ t,
                              const float* __restrict__ b, float* __restrict__ out) {
    int node = (blockIdx.x * blockDim.x + threadIdx.x) >> 6;
    int lane = threadIdx.x & 63;
    if (node >= N_NODES) return;
    int sub = lane >> 4, l16 = lane & 15;
    int beg = rowptr[node], end = rowptr[node + 1];
    const float4* __restrict__ t4 = (const float4*)t;
    float4 acc = {0.f, 0.f, 0.f, 0.f};
    for (int p0 = beg; p0 < end; p0 += 4) {
        int p = p0 + sub;
        if (p < end) {
            int s = csr_src[p];
            float nm = csr_norm[p];
            float4 v = t4[(size_t)s * 16 + l16];
            acc.x = fmaf(nm, v.x, acc.x);
            acc.y = fmaf(nm, v.y, acc.y);
            acc.z = fmaf(nm, v.z, acc.z);
            acc.w = fmaf(nm, v.w, acc.w);
        }
    }
#pragma unroll
    for (int m = 16; m <= 32; m <<= 1) {
        acc.x += __shfl_xor(acc.x, m);
        acc.y += __shfl_xor(acc.y, m);
        acc.z += __shfl_xor(acc.z, m);
        acc.w += __shfl_xor(acc.w, m);
    }
    if (lane < 16) {
        float4 bv = ((const float4*)b)[l16];
        float4 r;
        r.x = fmaxf(acc.x + bv.x, 0.f);
        r.y = fmaxf(acc.y + bv.y, 0.f);
        r.z = fmaxf(acc.z + bv.z, 0.f);
        r.w = fmaxf(acc.w + bv.w, 0.f);
        ((float4*)out)[(size_t)node * 16 + l16] = r;
    }
}

// ---------------- GAT ----------------
// wat[q*64 + cin] = sum_c gat_w[cin, h*64+c] * att[h][c],  q = h*2 + (0:src,1:dst)
__global__ void k_wat(const float* __restrict__ gat_w, const float* __restrict__ att_src,
                      const float* __restrict__ att_dst, float* __restrict__ wat) {
    int t = threadIdx.x;  // 512 threads
    int q = t >> 6, cin = t & 63;
    int h = q >> 1;
    const float* av = (q & 1) ? att_dst : att_src;
    float acc = 0.f;
#pragma unroll
    for (int c = 0; c < 64; ++c)
        acc = fmaf(gat_w[cin * 256 + h * 64 + c], av[h * 64 + c], acc);
    wat[t] = acc;
}

// wbig[(h*64+cin)*64 + c] = 0.25 * gat_w[cin*256 + h*64 + c]
__global__ void k_wbig(const float* __restrict__ gat_w, float* __restrict__ wbig) {
    int i = blockIdx.x * 256 + threadIdx.x;
    if (i >= 256 * 64) return;
    int k = i >> 6, c = i & 63;
    int h = k >> 6, cin = k & 63;
    wbig[i] = 0.25f * gat_w[cin * 256 + h * 64 + c];
}

// asrc/adst = bufA @ wat^T : wave per node
__global__ void k_att2(const float* __restrict__ xin, const float* __restrict__ wat,
                       float* __restrict__ asrc, float* __restrict__ adst) {
    __shared__ float sw[512];
    for (int i = threadIdx.x; i < 512; i += 256) sw[i] = wat[i];
    __syncthreads();
    int node = (blockIdx.x * blockDim.x + threadIdx.x) >> 6;
    int lane = threadIdx.x & 63;
    if (node >= N_NODES) return;
    float val = xin[(size_t)node * 64 + lane];
#pragma unroll
    for (int q = 0; q < 8; ++q) {
        float p = val * sw[q * 64 + lane];
#pragma unroll
        for (int m = 1; m <= 32; m <<= 1) p += __shfl_xor(p, m);
        if (lane == q) {
            if (q & 1) adst[node * 4 + (q >> 1)] = p;
            else       asrc[node * 4 + (q >> 1)] = p;
        }
    }
}

static __device__ __forceinline__ float lrelu02(float v) {
    return v >= 0.f ? v : 0.2f * v;
}

// per (edge,head) unnormalized exp + per (node,head) denominator
__global__ void k_gat_alpha(const int* __restrict__ rowptr, const int* __restrict__ csr_src,
                            const float* __restrict__ asrc, const float* __restrict__ adst,
                            float* __restrict__ ebuf, float* __restrict__ denom) {
    int node = (blockIdx.x * blockDim.x + threadIdx.x) >> 6;
    int lane = threadIdx.x & 63;
    if (node >= N_NODES) return;
    int h = lane & 3, esub = lane >> 2;  // 16 edges x 4 heads per pass
    int beg = rowptr[node], end = rowptr[node + 1];
    float ad = adst[node * 4 + h];
    float m = -1e30f;
    for (int base = beg; base < end; base += 16) {
        int e = base + esub;
        if (e < end) {
            int s = csr_src[e];
            m = fmaxf(m, lrelu02(asrc[s * 4 + h] + ad));
        }
    }
#pragma unroll
    for (int mk = 4; mk <= 32; mk <<= 1) m = fmaxf(m, __shfl_xor(m, mk));
    float den = 0.f;
    for (int base = beg; base < end; base += 16) {
        int e = base + esub;
        if (e < end) {
            int s = csr_src[e];
            float ex = expf(lrelu02(asrc[s * 4 + h] + ad) - m);
            den += ex;
            ebuf[e * 4 + h] = ex;  // == base*4 + lane : coalesced
        }
    }
#pragma unroll
    for (int mk = 4; mk <= 32; mk <<= 1) den += __shfl_xor(den, mk);
    if (lane < 4) denom[node * 4 + lane] = den;
}

// per-head normalized weighted sum of bufA rows: Pcat[node, h*64+c] (lane: h=lane>>4)
__global__ void k_gat_wsum(const int* __restrict__ rowptr, const int* __restrict__ csr_src,
                           const float* __restrict__ ebuf, const float* __restrict__ denom,
                           const float* __restrict__ bufA, float* __restrict__ pcat) {
    int node = (blockIdx.x * blockDim.x + threadIdx.x) >> 6;
    int lane = threadIdx.x & 63;
    if (node >= N_NODES) return;
    int h = lane >> 4, l16 = lane & 15;
    int beg = rowptr[node], end = rowptr[node + 1];
    const float4* __restrict__ a4 = (const float4*)bufA;
    float4 acc = {0.f, 0.f, 0.f, 0.f};
    for (int p = beg; p < end; ++p) {
        int s = csr_src[p];
        float a = ebuf[p * 4 + h];
        float4 v = a4[(size_t)s * 16 + l16];  // broadcast across the 4 head groups
        acc.x = fmaf(a, v.x, acc.x);
        acc.y = fmaf(a, v.y, acc.y);
        acc.z = fmaf(a, v.z, acc.z);
        acc.w = fmaf(a, v.w, acc.w);
    }
    float inv = 1.0f / denom[node * 4 + h];
    acc.x *= inv; acc.y *= inv; acc.z *= inv; acc.w *= inv;
    ((float4*)pcat)[(size_t)node * 64 + lane] = acc;  // = node*256 + h*64 + l16*4
}

// ---------------- pool (batch sorted: run-length accumulate, 32 nodes/wave) ----------------
__global__ void k_pool2(const int* __restrict__ batch, const float* __restrict__ h,
                        float* __restrict__ psum, float* __restrict__ pcnt) {
    int wave = (blockIdx.x * blockDim.x + threadIdx.x) >> 6;
    int lane = threadIdx.x & 63;
    int n0 = wave * 32;
    if (n0 >= N_NODES) return;
    int nend = min(n0 + 32, N_NODES);
    int cur = batch[n0];
    float acc = 0.f, cnt = 0.f;
    for (int n = n0; n < nend; ++n) {
        int g = batch[n];
        if (g != cur) {
            atomicAdd(&psum[cur * 64 + lane], acc);
            if (lane == 0) atomicAdd(&pcnt[cur], cnt);
            acc = 0.f; cnt = 0.f; cur = g;
        }
        acc += h[(size_t)n * 64 + lane];
        cnt += 1.f;
    }
    atomicAdd(&psum[cur * 64 + lane], acc);
    if (lane == 0) atomicAdd(&pcnt[cur], cnt);
}

__global__ void k_cls(const float* __restrict__ psum, const float* __restrict__ pcnt,
                      const float* __restrict__ cw1, const float* __restrict__ cb1,
                      const float* __restrict__ cw2, const float* __restrict__ cb2,
                      float* __restrict__ out) {
    int g = blockIdx.x;
    int j = threadIdx.x;
    __shared__ float sp[64];
    float rc = 1.0f / fmaxf(pcnt[g], 1.0f);
    sp[j] = psum[g * 64 + j] * rc;
    __syncthreads();
    float z = 0.f;
    if (j < 32) {
        float acc = 0.f;
#pragma unroll
        for (int k = 0; k < 64; ++k) acc = fmaf(sp[k], cw1[k * 32 + j], acc);
        acc += cb1[j];
        acc = fmaxf(acc, 0.f);
        z = acc * cw2[j];
    }
#pragma unroll
    for (int off = 32; off; off >>= 1) z += __shfl_down(z, off);
    if (j == 0) out[g] = z + cb2[0];
}

extern "C" void kernel_launch(void* const* d_in, const int* in_sizes, int n_in,
                              void* d_out, int out_size, void* d_ws, size_t ws_size,
                              hipStream_t stream) {
    const float* x       = (const float*)d_in[0];
    const int*   ei      = (const int*)d_in[1];
    const int*   batch   = (const int*)d_in[2];
    const float* w1      = (const float*)d_in[3];
    const float* b1      = (const float*)d_in[4];
    const float* w2      = (const float*)d_in[5];
    const float* b2      = (const float*)d_in[6];
    const float* w3      = (const float*)d_in[7];
    const float* b3      = (const float*)d_in[8];
    const float* gat_w   = (const float*)d_in[9];
    const float* att_src = (const float*)d_in[10];
    const float* att_dst = (const float*)d_in[11];
    const float* gat_b   = (const float*)d_in[12];
    const float* cw1     = (const float*)d_in[13];
    const float* cb1     = (const float*)d_in[14];
    const float* cw2     = (const float*)d_in[15];
    const float* cb2     = (const float*)d_in[16];
    float* out = (float*)d_out;

    const int* srcp = ei;
    const int* dstp = ei + N_EDGES;

    float* W = (float*)d_ws;
    size_t off = 0;
    float*    dinv    = W + off; off += N_NODES;
    int*      degi    = (int*)(W + off); off += N_NODES;
    int*      rowptr  = (int*)(W + off); off += N_NODES + 1;
    int*      partial = (int*)(W + off); off += 256;
    int*      cursor  = (int*)(W + off); off += N_NODES;
    int*      csr_src = (int*)(W + off); off += E_TOT;
    float*    csr_nrm = W + off; off += E_TOT;
    float*    bufT    = W + off; off += (size_t)N_NODES * HID;
    float*    bufA    = W + off; off += (size_t)N_NODES * HID;
    float*    bufB    = W + off; off += (size_t)N_NODES * HID;
    float*    pcat    = W + off; off += (size_t)N_NODES * 256;
    float*    asrc    = W + off; off += (size_t)N_NODES * 4;
    float*    adst    = W + off; off += (size_t)N_NODES * 4;
    float*    ebuf    = W + off; off += (size_t)E_TOT * 4;
    float*    denom   = W + off; off += (size_t)N_NODES * 4;
    float*    wat     = W + off; off += 512;
    float*    wbig    = W + off; off += 256 * 64;
    float*    psum    = W + off; off += (size_t)N_GRAPHS * HID;
    float*    pcnt    = W + off; off += N_GRAPHS;

    auto cdiv = [](int a, int b) { return (a + b - 1) / b; };

    hipMemsetAsync(degi, 0, N_NODES * sizeof(int), stream);
    hipMemsetAsync(psum, 0, (N_GRAPHS * HID + N_GRAPHS) * sizeof(float), stream);

    // degree / dinv / CSR
    k_deg<<<cdiv(N_EDGES, 256), 256, 0, stream>>>(dstp, degi);
    k_dinv<<<cdiv(N_NODES, 256), 256, 0, stream>>>(degi, dinv);
    k_scan1<<<SCAN_NB, 256, 0, stream>>>(degi, rowptr, partial);
    k_scan2<<<1, 256, 0, stream>>>(partial);
    k_scan3<<<SCAN_NB, 256, 0, stream>>>(rowptr, partial);
    k_fill_self<<<cdiv(N_NODES, 256), 256, 0, stream>>>(rowptr, dinv, csr_src, csr_nrm, cursor);
    k_fill_edge<<<cdiv(N_EDGES, 256), 256, 0, stream>>>(srcp, dstp, rowptr, dinv, cursor,
                                                        csr_src, csr_nrm);

    const int nWV = cdiv(N_NODES * 64, 256);   // wave-per-node kernels
    const int nGB = cdiv(N_NODES, 64);         // gemm blocks

    // GCN layer 1 (K=128): x -> bufA
    k_gemm_v3<F_IN, false><<<nGB, 256, 0, stream>>>(x, w1, nullptr, bufT, N_NODES);
    k_gcn_gather4<<<nWV, 256, 0, stream>>>(rowptr, csr_src, csr_nrm, bufT, b1, bufA);

    // GCN layer 2: bufA -> bufB
    k_gemm_v3<HID, false><<<nGB, 256, 0, stream>>>(bufA, w2, nullptr, bufT, N_NODES);
    k_gcn_gather4<<<nWV, 256, 0, stream>>>(rowptr, csr_src, csr_nrm, bufT, b2, bufB);

    // GCN layer 3: bufB -> bufA
    k_gemm_v3<HID, false><<<nGB, 256, 0, stream>>>(bufB, w3, nullptr, bufT, N_NODES);
    k_gcn_gather4<<<nWV, 256, 0, stream>>>(rowptr, csr_src, csr_nrm, bufT, b3, bufA);

    // GAT (no hg materialization: aggregate bufA per head, then one [N,256]@[256,64] GEMM)
    k_wat<<<1, 512, 0, stream>>>(gat_w, att_src, att_dst, wat);
    k_wbig<<<64, 256, 0, stream>>>(gat_w, wbig);
    k_att2<<<nWV, 256, 0, stream>>>(bufA, wat, asrc, adst);
    k_gat_alpha<<<nWV, 256, 0, stream>>>(rowptr, csr_src, asrc, adst, ebuf, denom);
    k_gat_wsum<<<nWV, 256, 0, stream>>>(rowptr, csr_src, ebuf, denom, bufA, pcat);
    k_gemm_v3<256, true><<<nGB, 256, 0, stream>>>(pcat, wbig, gat_b, bufB, N_NODES);

    // pool + classifier
    k_pool2<<<cdiv(cdiv(N_NODES, 32) * 64, 256), 256, 0, stream>>>(batch, bufB, psum, pcnt);
    k_cls<<<N_GRAPHS, 64, 0, stream>>>(psum, pcnt, cw1, cb1, cw2, cb2, out);
}

// Round 9
// 448.092 us; speedup vs baseline: 1.9876x; 1.0262x over previous
//
#include <hip/hip_runtime.h>
#include <hip/hip_bf16.h>

#define N_NODES 50000
#define N_EDGES 400000
#define E_TOT   450000   // + self loops
#define N_GRAPHS 256
#define F_IN 128
#define HID 64
#define SCAN_NB 196      // ceil(50000/256)

#define FMA4(A, S, W)               \
    A.x = fmaf(S, W.x, A.x);        \
    A.y = fmaf(S, W.y, A.y);        \
    A.z = fmaf(S, W.z, A.z);        \
    A.w = fmaf(S, W.w, A.w);

static __device__ __forceinline__ float lrelu02(float v) {
    return v >= 0.f ? v : 0.2f * v;
}

// ---------------- degree ----------------
__global__ void k_deg(const int* __restrict__ dstp, int* __restrict__ degi) {
    int e = blockIdx.x * blockDim.x + threadIdx.x;
    if (e < N_EDGES) atomicAdd(&degi[dstp[e]], 1);
}

// ---------------- CSR build: exclusive scan of (deg+1); dinv fused ----------------
__global__ void k_scan1(const int* __restrict__ degi, int* __restrict__ rowptr,
                        int* __restrict__ partial, float* __restrict__ dinv) {
    __shared__ int s[256];
    int i = blockIdx.x * 256 + threadIdx.x;
    int v = (i < N_NODES) ? (degi[i] + 1) : 0;
    s[threadIdx.x] = v;
    __syncthreads();
    for (int off = 1; off < 256; off <<= 1) {
        int t = (threadIdx.x >= off) ? s[threadIdx.x - off] : 0;
        __syncthreads();
        s[threadIdx.x] += t;
        __syncthreads();
    }
    if (i < N_NODES) {
        rowptr[i] = s[threadIdx.x] - v;
        dinv[i] = rsqrtf((float)v);  // v = deg + 1 (self loop)
    }
    if (threadIdx.x == 255) partial[blockIdx.x] = s[255];
}

__global__ void k_scan2(int* __restrict__ partial) {
    __shared__ int s[256];
    int v = (threadIdx.x < SCAN_NB) ? partial[threadIdx.x] : 0;
    s[threadIdx.x] = v;
    __syncthreads();
    for (int off = 1; off < 256; off <<= 1) {
        int t = (threadIdx.x >= off) ? s[threadIdx.x - off] : 0;
        __syncthreads();
        s[threadIdx.x] += t;
        __syncthreads();
    }
    if (threadIdx.x < SCAN_NB) partial[threadIdx.x] = s[threadIdx.x] - v;
}

// final rowptr + self-loop fill + cursor init (fused)
__global__ void k_scan3(int* __restrict__ rowptr, const int* __restrict__ partial,
                        const float* __restrict__ dinv, int* __restrict__ csr_src,
                        float* __restrict__ csr_norm, int* __restrict__ cursor) {
    int i = blockIdx.x * 256 + threadIdx.x;
    if (i < N_NODES) {
        int rp = rowptr[i] + partial[blockIdx.x];
        rowptr[i] = rp;
        csr_src[rp] = i;
        float di = dinv[i];
        csr_norm[rp] = di * di;
        cursor[i] = 1;
    }
    if (i == 0) rowptr[N_NODES] = E_TOT;
}

__global__ void k_fill_edge(const int* __restrict__ srcp, const int* __restrict__ dstp,
                            const int* __restrict__ rowptr, const float* __restrict__ dinv,
                            int* __restrict__ cursor, int* __restrict__ csr_src,
                            float* __restrict__ csr_norm) {
    int e = blockIdx.x * blockDim.x + threadIdx.x;
    if (e >= N_EDGES) return;
    int s = srcp[e], d = dstp[e];
    int p = rowptr[d] + atomicAdd(&cursor[d], 1);
    csr_src[p] = s;
    csr_norm[p] = dinv[s] * dinv[d];
}

// ---------------- tiled GEMM: out[N,64] = x[N,K] @ w[K,64]  (+bias, relu if EPI) ----------
template <int K, bool EPI>
__global__ __launch_bounds__(256) void k_gemm_v3(
        const float* __restrict__ x, const float* __restrict__ w,
        const float* __restrict__ bias, float* __restrict__ out, int nrows) {
    __shared__ float sw[64 * 64];
    const int tid = threadIdx.x;
    const int wave = tid >> 6, lane = tid & 63;
    const int g = lane >> 4, l16 = lane & 15;
    const int c0 = l16 * 4;
    const int r0 = blockIdx.x * 64 + wave * 16 + g * 4;
    constexpr int KV = K / 4;
    const int last = nrows - 1;
    const float4* __restrict__ x4 = (const float4*)x;
    const float4* __restrict__ p0 = x4 + (size_t)min(r0 + 0, last) * KV;
    const float4* __restrict__ p1 = x4 + (size_t)min(r0 + 1, last) * KV;
    const float4* __restrict__ p2 = x4 + (size_t)min(r0 + 2, last) * KV;
    const float4* __restrict__ p3 = x4 + (size_t)min(r0 + 3, last) * KV;
    float4 a0 = make_float4(0.f, 0.f, 0.f, 0.f);
    float4 a1 = a0, a2 = a0, a3 = a0;

    for (int kt = 0; kt < K / 64; ++kt) {
        __syncthreads();
        for (int i = tid; i < 64 * 64; i += 256) {
            int k = i >> 6, j = i & 63;
            sw[i] = w[(kt * 64 + k) * 64 + j];
        }
        __syncthreads();
        const int kb = kt * 16;
#pragma unroll 4
        for (int k4 = 0; k4 < 16; ++k4) {
            float4 xv0 = p0[kb + k4];
            float4 xv1 = p1[kb + k4];
            float4 xv2 = p2[kb + k4];
            float4 xv3 = p3[kb + k4];
            const float* swp = &sw[(k4 * 4) * 64 + c0];
            float4 wv0 = *(const float4*)(swp);
            float4 wv1 = *(const float4*)(swp + 64);
            float4 wv2 = *(const float4*)(swp + 128);
            float4 wv3 = *(const float4*)(swp + 192);
            FMA4(a0, xv0.x, wv0) FMA4(a1, xv1.x, wv0) FMA4(a2, xv2.x, wv0) FMA4(a3, xv3.x, wv0)
            FMA4(a0, xv0.y, wv1) FMA4(a1, xv1.y, wv1) FMA4(a2, xv2.y, wv1) FMA4(a3, xv3.y, wv1)
            FMA4(a0, xv0.z, wv2) FMA4(a1, xv1.z, wv2) FMA4(a2, xv2.z, wv2) FMA4(a3, xv3.z, wv2)
            FMA4(a0, xv0.w, wv3) FMA4(a1, xv1.w, wv3) FMA4(a2, xv2.w, wv3) FMA4(a3, xv3.w, wv3)
        }
    }
    float4 bv = make_float4(0.f, 0.f, 0.f, 0.f);
    if (EPI) bv = *(const float4*)(bias + c0);
    if (EPI) {
        a0.x = fmaxf(a0.x + bv.x, 0.f); a0.y = fmaxf(a0.y + bv.y, 0.f);
        a0.z = fmaxf(a0.z + bv.z, 0.f); a0.w = fmaxf(a0.w + bv.w, 0.f);
        a1.x = fmaxf(a1.x + bv.x, 0.f); a1.y = fmaxf(a1.y + bv.y, 0.f);
        a1.z = fmaxf(a1.z + bv.z, 0.f); a1.w = fmaxf(a1.w + bv.w, 0.f);
        a2.x = fmaxf(a2.x + bv.x, 0.f); a2.y = fmaxf(a2.y + bv.y, 0.f);
        a2.z = fmaxf(a2.z + bv.z, 0.f); a2.w = fmaxf(a2.w + bv.w, 0.f);
        a3.x = fmaxf(a3.x + bv.x, 0.f); a3.y = fmaxf(a3.y + bv.y, 0.f);
        a3.z = fmaxf(a3.z + bv.z, 0.f); a3.w = fmaxf(a3.w + bv.w, 0.f);
    }
    if (r0 + 0 < nrows) *(float4*)(out + (size_t)(r0 + 0) * 64 + c0) = a0;
    if (r0 + 1 < nrows) *(float4*)(out + (size_t)(r0 + 1) * 64 + c0) = a1;
    if (r0 + 2 < nrows) *(float4*)(out + (size_t)(r0 + 2) * 64 + c0) = a2;
    if (r0 + 3 < nrows) *(float4*)(out + (size_t)(r0 + 3) * 64 + c0) = a3;
}

// ---------------- GCN aggregate: grid-stride wave/node, 4 edges/pass, idx prefetch ----------
// Per-node arithmetic identical to round-5's k_gcn_gather4 (same per-lane edge set/order).
__global__ __launch_bounds__(256) void k_gcn_gather_v3(
        const int* __restrict__ rowptr, const int* __restrict__ csr_src,
        const float* __restrict__ csr_norm, const float* __restrict__ t,
        const float* __restrict__ b, float* __restrict__ out) {
    const int gw = (blockIdx.x * 256 + threadIdx.x) >> 6;
    const int nw = (gridDim.x * 256) >> 6;
    const int lane = threadIdx.x & 63;
    const int sub = lane >> 4, l16 = lane & 15;
    const float4* __restrict__ t4 = (const float4*)t;
    const float4 bv = ((const float4*)b)[l16];
    for (int node = gw; node < N_NODES; node += nw) {
        int beg = rowptr[node], end = rowptr[node + 1];
        float4 acc = make_float4(0.f, 0.f, 0.f, 0.f);
        int p = beg + sub;
        bool vc = p < end;
        int sc = 0; float nc = 0.f;
        if (vc) { sc = csr_src[p]; nc = csr_norm[p]; }
        while (vc) {
            int pn = p + 4;
            bool vn = pn < end;
            int sn = 0; float nn = 0.f;
            if (vn) { sn = csr_src[pn]; nn = csr_norm[pn]; }
            float4 v = t4[(size_t)sc * 16 + l16];
            acc.x = fmaf(nc, v.x, acc.x);
            acc.y = fmaf(nc, v.y, acc.y);
            acc.z = fmaf(nc, v.z, acc.z);
            acc.w = fmaf(nc, v.w, acc.w);
            p = pn; vc = vn; sc = sn; nc = nn;
        }
#pragma unroll
        for (int m = 16; m <= 32; m <<= 1) {
            acc.x += __shfl_xor(acc.x, m);
            acc.y += __shfl_xor(acc.y, m);
            acc.z += __shfl_xor(acc.z, m);
            acc.w += __shfl_xor(acc.w, m);
        }
        if (lane < 16) {
            float4 r;
            r.x = fmaxf(acc.x + bv.x, 0.f);
            r.y = fmaxf(acc.y + bv.y, 0.f);
            r.z = fmaxf(acc.z + bv.z, 0.f);
            r.w = fmaxf(acc.w + bv.w, 0.f);
            ((float4*)out)[(size_t)node * 16 + l16] = r;
        }
    }
}

// ---------------- GAT: wat (folded logit weights) + wbig (0.25*gat_w reshaped) ------------
__global__ void k_wat2(const float* __restrict__ gat_w, const float* __restrict__ att_src,
                       const float* __restrict__ att_dst, float* __restrict__ wat,
                       float* __restrict__ wbig) {
    int t = threadIdx.x;  // 512 threads
    int q = t >> 6, cin = t & 63;
    int h = q >> 1;
    const float* av = (q & 1) ? att_dst : att_src;
    float acc = 0.f;
#pragma unroll
    for (int c = 0; c < 64; ++c)
        acc = fmaf(gat_w[cin * 256 + h * 64 + c], av[h * 64 + c], acc);
    wat[t] = acc;
    for (int i = t; i < 256 * 64; i += 512) {
        int k = i >> 6, c = i & 63;
        int hh = k >> 6, ci = k & 63;
        wbig[i] = 0.25f * gat_w[ci * 256 + hh * 64 + c];
    }
}

// asrc/adst = bufA @ wat^T : wave per node (round-5 proven kernel, verbatim)
__global__ void k_att2(const float* __restrict__ xin, const float* __restrict__ wat,
                       float* __restrict__ asrc, float* __restrict__ adst) {
    __shared__ float sw[512];
    for (int i = threadIdx.x; i < 512; i += 256) sw[i] = wat[i];
    __syncthreads();
    int node = (blockIdx.x * blockDim.x + threadIdx.x) >> 6;
    int lane = threadIdx.x & 63;
    if (node >= N_NODES) return;
    float val = xin[(size_t)node * 64 + lane];
#pragma unroll
    for (int q = 0; q < 8; ++q) {
        float p = val * sw[q * 64 + lane];
#pragma unroll
        for (int m = 1; m <= 32; m <<= 1) p += __shfl_xor(p, m);
        if (lane == q) {
            if (q & 1) adst[node * 4 + (q >> 1)] = p;
            else       asrc[node * 4 + (q >> 1)] = p;
        }
    }
}

// per (edge,head) unnormalized exp + per (node,head) denominator (round-5 body, grid-stride)
__global__ __launch_bounds__(256) void k_gat_alpha(
        const int* __restrict__ rowptr, const int* __restrict__ csr_src,
        const float* __restrict__ asrc, const float* __restrict__ adst,
        float* __restrict__ ebuf, float* __restrict__ denom) {
    const int gw = (blockIdx.x * 256 + threadIdx.x) >> 6;
    const int nw = (gridDim.x * 256) >> 6;
    const int lane = threadIdx.x & 63;
    const int h = lane & 3, esub = lane >> 2;  // 16 edges x 4 heads per pass
    for (int node = gw; node < N_NODES; node += nw) {
        int beg = rowptr[node], end = rowptr[node + 1];
        float ad = adst[node * 4 + h];
        float m = -1e30f;
        for (int base = beg; base < end; base += 16) {
            int e = base + esub;
            if (e < end) {
                int s = csr_src[e];
                m = fmaxf(m, lrelu02(asrc[s * 4 + h] + ad));
            }
        }
#pragma unroll
        for (int mk = 4; mk <= 32; mk <<= 1) m = fmaxf(m, __shfl_xor(m, mk));
        float den = 0.f;
        for (int base = beg; base < end; base += 16) {
            int e = base + esub;
            if (e < end) {
                int s = csr_src[e];
                float ex = expf(lrelu02(asrc[s * 4 + h] + ad) - m);
                den += ex;
                ebuf[e * 4 + h] = ex;  // == base*4 + lane : coalesced
            }
        }
#pragma unroll
        for (int mk = 4; mk <= 32; mk <<= 1) den += __shfl_xor(den, mk);
        if (lane < 4) denom[node * 4 + lane] = den;
    }
}

// per-head normalized weighted sum of bufA rows -> Pcat[node, h*64+c]
// (round-5 body: lane owns head=lane>>4, feats (lane&15)*4..+3; grid-stride + 2-deep prefetch)
__global__ __launch_bounds__(256) void k_gat_wsum(
        const int* __restrict__ rowptr, const int* __restrict__ csr_src,
        const float* __restrict__ ebuf, const float* __restrict__ denom,
        const float* __restrict__ bufA, float* __restrict__ pcat) {
    const int gw = (blockIdx.x * 256 + threadIdx.x) >> 6;
    const int nw = (gridDim.x * 256) >> 6;
    const int lane = threadIdx.x & 63;
    const int h = lane >> 4, l16 = lane & 15;
    const float4* __restrict__ a4 = (const float4*)bufA;
    for (int node = gw; node < N_NODES; node += nw) {
        int beg = rowptr[node], end = rowptr[node + 1];
        float4 acc = make_float4(0.f, 0.f, 0.f, 0.f);
        int p = beg;
        int sc = csr_src[p];            // >=1 edge always (self loop)
        float ac = ebuf[p * 4 + h];
        while (p < end) {
            int pn = p + 1;
            int sn = 0; float an = 0.f;
            if (pn < end) { sn = csr_src[pn]; an = ebuf[pn * 4 + h]; }
            float4 v = a4[(size_t)sc * 16 + l16];
            acc.x = fmaf(ac, v.x, acc.x);
            acc.y = fmaf(ac, v.y, acc.y);
            acc.z = fmaf(ac, v.z, acc.z);
            acc.w = fmaf(ac, v.w, acc.w);
            p = pn; sc = sn; ac = an;
        }
        float inv = 1.0f / denom[node * 4 + h];
        acc.x *= inv; acc.y *= inv; acc.z *= inv; acc.w *= inv;
        ((float4*)pcat)[(size_t)node * 64 + lane] = acc;  // = node*256 + h*64 + l16*4
    }
}

// ---------------- pool (batch sorted: run-length accumulate, 32 nodes/wave) ----------------
__global__ void k_pool2(const int* __restrict__ batch, const float* __restrict__ h,
                        float* __restrict__ psum, float* __restrict__ pcnt) {
    int wave = (blockIdx.x * blockDim.x + threadIdx.x) >> 6;
    int lane = threadIdx.x & 63;
    int n0 = wave * 32;
    if (n0 >= N_NODES) return;
    int nend = min(n0 + 32, N_NODES);
    int cur = batch[n0];
    float acc = 0.f, cnt = 0.f;
    for (int n = n0; n < nend; ++n) {
        int g = batch[n];
        if (g != cur) {
            atomicAdd(&psum[cur * 64 + lane], acc);
            if (lane == 0) atomicAdd(&pcnt[cur], cnt);
            acc = 0.f; cnt = 0.f; cur = g;
        }
        acc += h[(size_t)n * 64 + lane];
        cnt += 1.f;
    }
    atomicAdd(&psum[cur * 64 + lane], acc);
    if (lane == 0) atomicAdd(&pcnt[cur], cnt);
}

__global__ void k_cls(const float* __restrict__ psum, const float* __restrict__ pcnt,
                      const float* __restrict__ cw1, const float* __restrict__ cb1,
                      const float* __restrict__ cw2, const float* __restrict__ cb2,
                      float* __restrict__ out) {
    int g = blockIdx.x;
    int j = threadIdx.x;
    __shared__ float sp[64];
    float rc = 1.0f / fmaxf(pcnt[g], 1.0f);
    sp[j] = psum[g * 64 + j] * rc;
    __syncthreads();
    float z = 0.f;
    if (j < 32) {
        float acc = 0.f;
#pragma unroll
        for (int k = 0; k < 64; ++k) acc = fmaf(sp[k], cw1[k * 32 + j], acc);
        acc += cb1[j];
        acc = fmaxf(acc, 0.f);
        z = acc * cw2[j];
    }
#pragma unroll
    for (int off = 32; off; off >>= 1) z += __shfl_down(z, off);
    if (j == 0) out[g] = z + cb2[0];
}

extern "C" void kernel_launch(void* const* d_in, const int* in_sizes, int n_in,
                              void* d_out, int out_size, void* d_ws, size_t ws_size,
                              hipStream_t stream) {
    const float* x       = (const float*)d_in[0];
    const int*   ei      = (const int*)d_in[1];
    const int*   batch   = (const int*)d_in[2];
    const float* w1      = (const float*)d_in[3];
    const float* b1      = (const float*)d_in[4];
    const float* w2      = (const float*)d_in[5];
    const float* b2      = (const float*)d_in[6];
    const float* w3      = (const float*)d_in[7];
    const float* b3      = (const float*)d_in[8];
    const float* gat_w   = (const float*)d_in[9];
    const float* att_src = (const float*)d_in[10];
    const float* att_dst = (const float*)d_in[11];
    const float* gat_b   = (const float*)d_in[12];
    const float* cw1     = (const float*)d_in[13];
    const float* cb1     = (const float*)d_in[14];
    const float* cw2     = (const float*)d_in[15];
    const float* cb2     = (const float*)d_in[16];
    float* out = (float*)d_out;

    const int* srcp = ei;
    const int* dstp = ei + N_EDGES;

    // workspace (all chunks multiple-of-4 floats for float4 alignment)
    float* W = (float*)d_ws;
    size_t off = 0;
    float*    dinv    = W + off; off += N_NODES;
    int*      rowptr  = (int*)(W + off); off += N_NODES + 4;
    int*      partial = (int*)(W + off); off += 256;
    int*      cursor  = (int*)(W + off); off += N_NODES;
    int*      csr_src = (int*)(W + off); off += E_TOT;
    float*    csr_nrm = W + off; off += E_TOT;
    float*    bufT    = W + off; off += (size_t)N_NODES * HID;
    float*    bufA    = W + off; off += (size_t)N_NODES * HID;
    float*    bufB    = W + off; off += (size_t)N_NODES * HID;
    float*    pcat    = W + off; off += (size_t)N_NODES * 256;
    float*    asrc    = W + off; off += (size_t)N_NODES * 4;
    float*    adst    = W + off; off += (size_t)N_NODES * 4;
    float*    ebuf    = W + off; off += (size_t)E_TOT * 4;
    float*    denom   = W + off; off += (size_t)N_NODES * 4;
    float*    wat     = W + off; off += 512;
    float*    wbig    = W + off; off += 256 * 64;
    // contiguous zero-init region: degi + psum + pcnt
    int*      degi    = (int*)(W + off); off += N_NODES;
    float*    psum    = W + off; off += (size_t)N_GRAPHS * HID;
    float*    pcnt    = W + off; off += N_GRAPHS;

    auto cdiv = [](int a, int b) { return (a + b - 1) / b; };

    hipMemsetAsync(degi, 0, (N_NODES + N_GRAPHS * HID + N_GRAPHS) * sizeof(int), stream);

    // degree / CSR (dinv fused into scan1, self-loop fill into scan3)
    k_deg<<<cdiv(N_EDGES, 256), 256, 0, stream>>>(dstp, degi);
    k_scan1<<<SCAN_NB, 256, 0, stream>>>(degi, rowptr, partial, dinv);
    k_scan2<<<1, 256, 0, stream>>>(partial);
    k_scan3<<<SCAN_NB, 256, 0, stream>>>(rowptr, partial, dinv, csr_src, csr_nrm, cursor);
    k_fill_edge<<<cdiv(N_EDGES, 256), 256, 0, stream>>>(srcp, dstp, rowptr, dinv, cursor,
                                                        csr_src, csr_nrm);
    k_wat2<<<1, 512, 0, stream>>>(gat_w, att_src, att_dst, wat, wbig);

    const int nGS = 2048;                  // grid-stride blocks
    const int nWV = cdiv(N_NODES * 64, 256);
    const int nGB = cdiv(N_NODES, 64);     // gemm blocks

    // GCN layer 1 (K=128): x -> bufA
    k_gemm_v3<F_IN, false><<<nGB, 256, 0, stream>>>(x, w1, nullptr, bufT, N_NODES);
    k_gcn_gather_v3<<<nGS, 256, 0, stream>>>(rowptr, csr_src, csr_nrm, bufT, b1, bufA);
    // GCN layer 2: bufA -> bufB
    k_gemm_v3<HID, false><<<nGB, 256, 0, stream>>>(bufA, w2, nullptr, bufT, N_NODES);
    k_gcn_gather_v3<<<nGS, 256, 0, stream>>>(rowptr, csr_src, csr_nrm, bufT, b2, bufB);
    // GCN layer 3: bufB -> bufA
    k_gemm_v3<HID, false><<<nGB, 256, 0, stream>>>(bufB, w3, nullptr, bufT, N_NODES);
    k_gcn_gather_v3<<<nGS, 256, 0, stream>>>(rowptr, csr_src, csr_nrm, bufT, b3, bufA);

    // GAT (proven round-5 kernels: att2 -> alpha -> wsum), then [N,256]@[256,64] GEMM
    k_att2<<<nWV, 256, 0, stream>>>(bufA, wat, asrc, adst);
    k_gat_alpha<<<nGS, 256, 0, stream>>>(rowptr, csr_src, asrc, adst, ebuf, denom);
    k_gat_wsum<<<nGS, 256, 0, stream>>>(rowptr, csr_src, ebuf, denom, bufA, pcat);
    k_gemm_v3<256, true><<<nGB, 256, 0, stream>>>(pcat, wbig, gat_b, bufB, N_NODES);

    // pool + classifier
    k_pool2<<<cdiv(cdiv(N_NODES, 32) * 64, 256), 256, 0, stream>>>(batch, bufB, psum, pcnt);
    k_cls<<<N_GRAPHS, 64, 0, stream>>>(psum, pcnt, cw1, cb1, cw2, cb2, out);
}

// Round 10
// 426.917 us; speedup vs baseline: 2.0862x; 1.0496x over previous
//
#include <hip/hip_runtime.h>
#include <hip/hip_bf16.h>

#define N_NODES 50000
#define N_EDGES 400000
#define E_TOT   450000   // + self loops
#define N_GRAPHS 256
#define F_IN 128
#define HID 64
#define SCAN_NB 196      // ceil(50000/256)

#define FMA4(A, S, W)               \
    A.x = fmaf(S, W.x, A.x);        \
    A.y = fmaf(S, W.y, A.y);        \
    A.z = fmaf(S, W.z, A.z);        \
    A.w = fmaf(S, W.w, A.w);

#define RED4(A, M)                  \
    A.x += __shfl_xor(A.x, M);      \
    A.y += __shfl_xor(A.y, M);      \
    A.z += __shfl_xor(A.z, M);      \
    A.w += __shfl_xor(A.w, M);

static __device__ __forceinline__ float lrelu02(float v) {
    return v >= 0.f ? v : 0.2f * v;
}

// ---------------- degree ----------------
__global__ void k_deg(const int* __restrict__ dstp, int* __restrict__ degi) {
    int e = blockIdx.x * blockDim.x + threadIdx.x;
    if (e < N_EDGES) atomicAdd(&degi[dstp[e]], 1);
}

// ---------------- CSR build: exclusive scan of (deg+1); dinv fused ----------------
__global__ void k_scan1(const int* __restrict__ degi, int* __restrict__ rowptr,
                        int* __restrict__ partial, float* __restrict__ dinv) {
    __shared__ int s[256];
    int i = blockIdx.x * 256 + threadIdx.x;
    int v = (i < N_NODES) ? (degi[i] + 1) : 0;
    s[threadIdx.x] = v;
    __syncthreads();
    for (int off = 1; off < 256; off <<= 1) {
        int t = (threadIdx.x >= off) ? s[threadIdx.x - off] : 0;
        __syncthreads();
        s[threadIdx.x] += t;
        __syncthreads();
    }
    if (i < N_NODES) {
        rowptr[i] = s[threadIdx.x] - v;
        dinv[i] = rsqrtf((float)v);  // v = deg + 1 (self loop)
    }
    if (threadIdx.x == 255) partial[blockIdx.x] = s[255];
}

__global__ void k_scan2(int* __restrict__ partial) {
    __shared__ int s[256];
    int v = (threadIdx.x < SCAN_NB) ? partial[threadIdx.x] : 0;
    s[threadIdx.x] = v;
    __syncthreads();
    for (int off = 1; off < 256; off <<= 1) {
        int t = (threadIdx.x >= off) ? s[threadIdx.x - off] : 0;
        __syncthreads();
        s[threadIdx.x] += t;
        __syncthreads();
    }
    if (threadIdx.x < SCAN_NB) partial[threadIdx.x] = s[threadIdx.x] - v;
}

// final rowptr + self-loop fill + cursor init (fused)
__global__ void k_scan3(int* __restrict__ rowptr, const int* __restrict__ partial,
                        const float* __restrict__ dinv, int* __restrict__ csr_src,
                        float* __restrict__ csr_norm, int* __restrict__ cursor) {
    int i = blockIdx.x * 256 + threadIdx.x;
    if (i < N_NODES) {
        int rp = rowptr[i] + partial[blockIdx.x];
        rowptr[i] = rp;
        csr_src[rp] = i;
        float di = dinv[i];
        csr_norm[rp] = di * di;
        cursor[i] = 1;
    }
    if (i == 0) rowptr[N_NODES] = E_TOT;
}

__global__ void k_fill_edge(const int* __restrict__ srcp, const int* __restrict__ dstp,
                            const int* __restrict__ rowptr, const float* __restrict__ dinv,
                            int* __restrict__ cursor, int* __restrict__ csr_src,
                            float* __restrict__ csr_norm) {
    int e = blockIdx.x * blockDim.x + threadIdx.x;
    if (e >= N_EDGES) return;
    int s = srcp[e], d = dstp[e];
    int p = rowptr[d] + atomicAdd(&cursor[d], 1);
    csr_src[p] = s;
    csr_norm[p] = dinv[s] * dinv[d];
}

// ---------------- tiled GEMM: out[N,64] = x[N,K] @ w[K,64]  (+bias, relu if EPI) ----------
template <int K, bool EPI>
__global__ __launch_bounds__(256) void k_gemm_v3(
        const float* __restrict__ x, const float* __restrict__ w,
        const float* __restrict__ bias, float* __restrict__ out, int nrows) {
    __shared__ float sw[64 * 64];
    const int tid = threadIdx.x;
    const int wave = tid >> 6, lane = tid & 63;
    const int g = lane >> 4, l16 = lane & 15;
    const int c0 = l16 * 4;
    const int r0 = blockIdx.x * 64 + wave * 16 + g * 4;
    constexpr int KV = K / 4;
    const int last = nrows - 1;
    const float4* __restrict__ x4 = (const float4*)x;
    const float4* __restrict__ p0 = x4 + (size_t)min(r0 + 0, last) * KV;
    const float4* __restrict__ p1 = x4 + (size_t)min(r0 + 1, last) * KV;
    const float4* __restrict__ p2 = x4 + (size_t)min(r0 + 2, last) * KV;
    const float4* __restrict__ p3 = x4 + (size_t)min(r0 + 3, last) * KV;
    float4 a0 = make_float4(0.f, 0.f, 0.f, 0.f);
    float4 a1 = a0, a2 = a0, a3 = a0;

    for (int kt = 0; kt < K / 64; ++kt) {
        __syncthreads();
        for (int i = tid; i < 64 * 64; i += 256) {
            int k = i >> 6, j = i & 63;
            sw[i] = w[(kt * 64 + k) * 64 + j];
        }
        __syncthreads();
        const int kb = kt * 16;
#pragma unroll 4
        for (int k4 = 0; k4 < 16; ++k4) {
            float4 xv0 = p0[kb + k4];
            float4 xv1 = p1[kb + k4];
            float4 xv2 = p2[kb + k4];
            float4 xv3 = p3[kb + k4];
            const float* swp = &sw[(k4 * 4) * 64 + c0];
            float4 wv0 = *(const float4*)(swp);
            float4 wv1 = *(const float4*)(swp + 64);
            float4 wv2 = *(const float4*)(swp + 128);
            float4 wv3 = *(const float4*)(swp + 192);
            FMA4(a0, xv0.x, wv0) FMA4(a1, xv1.x, wv0) FMA4(a2, xv2.x, wv0) FMA4(a3, xv3.x, wv0)
            FMA4(a0, xv0.y, wv1) FMA4(a1, xv1.y, wv1) FMA4(a2, xv2.y, wv1) FMA4(a3, xv3.y, wv1)
            FMA4(a0, xv0.z, wv2) FMA4(a1, xv1.z, wv2) FMA4(a2, xv2.z, wv2) FMA4(a3, xv3.z, wv2)
            FMA4(a0, xv0.w, wv3) FMA4(a1, xv1.w, wv3) FMA4(a2, xv2.w, wv3) FMA4(a3, xv3.w, wv3)
        }
    }
    float4 bv = make_float4(0.f, 0.f, 0.f, 0.f);
    if (EPI) bv = *(const float4*)(bias + c0);
    if (EPI) {
        a0.x = fmaxf(a0.x + bv.x, 0.f); a0.y = fmaxf(a0.y + bv.y, 0.f);
        a0.z = fmaxf(a0.z + bv.z, 0.f); a0.w = fmaxf(a0.w + bv.w, 0.f);
        a1.x = fmaxf(a1.x + bv.x, 0.f); a1.y = fmaxf(a1.y + bv.y, 0.f);
        a1.z = fmaxf(a1.z + bv.z, 0.f); a1.w = fmaxf(a1.w + bv.w, 0.f);
        a2.x = fmaxf(a2.x + bv.x, 0.f); a2.y = fmaxf(a2.y + bv.y, 0.f);
        a2.z = fmaxf(a2.z + bv.z, 0.f); a2.w = fmaxf(a2.w + bv.w, 0.f);
        a3.x = fmaxf(a3.x + bv.x, 0.f); a3.y = fmaxf(a3.y + bv.y, 0.f);
        a3.z = fmaxf(a3.z + bv.z, 0.f); a3.w = fmaxf(a3.w + bv.w, 0.f);
    }
    if (r0 + 0 < nrows) *(float4*)(out + (size_t)(r0 + 0) * 64 + c0) = a0;
    if (r0 + 1 < nrows) *(float4*)(out + (size_t)(r0 + 1) * 64 + c0) = a1;
    if (r0 + 2 < nrows) *(float4*)(out + (size_t)(r0 + 2) * 64 + c0) = a2;
    if (r0 + 3 < nrows) *(float4*)(out + (size_t)(r0 + 3) * 64 + c0) = a3;
}

// ---------------- GCN aggregate v4: 8 edges in flight, 3-stage pipeline ----------------
// lane = sub*8 + l8; sub owns edges beg+sub, beg+sub+8, ...; each lane covers half a row
// (cols l8*4..+3 and 32+l8*4..+3). Invalid slots use norm=0 (FMA adds 0; row 0 read is safe).
__global__ __launch_bounds__(256) void k_gcn_gather_v4(
        const int* __restrict__ rowptr, const int* __restrict__ csr_src,
        const float* __restrict__ csr_norm, const float* __restrict__ t,
        const float* __restrict__ b, float* __restrict__ out) {
    const int gw = (blockIdx.x * 256 + threadIdx.x) >> 6;
    const int nw = (gridDim.x * 256) >> 6;
    const int lane = threadIdx.x & 63;
    const int sub = lane >> 3, l8 = lane & 7;
    const float4* __restrict__ t4 = (const float4*)t;
    const float4* __restrict__ b4 = (const float4*)b;
    for (int node = gw; node < N_NODES; node += nw) {
        const int beg = rowptr[node], end = rowptr[node + 1];
        const int iters = (end - beg + 7) >> 3;
        float4 acca = make_float4(0.f, 0.f, 0.f, 0.f);
        float4 accb = acca;
        // stage 0: idx+val for it=0, idx for it=1
        int p0 = beg + sub;
        int s0 = 0; float n0 = 0.f;
        if (p0 < end) { s0 = csr_src[p0]; n0 = csr_norm[p0]; }
        float4 va0 = t4[(size_t)s0 * 16 + l8];
        float4 vb0 = t4[(size_t)s0 * 16 + 8 + l8];
        int p1 = p0 + 8;
        int s1 = 0; float n1 = 0.f;
        if (p1 < end) { s1 = csr_src[p1]; n1 = csr_norm[p1]; }
        for (int it = 0; it < iters; ++it) {
            // prefetch idx for it+2
            int p2 = p1 + 8;
            int s2 = 0; float n2 = 0.f;
            if (p2 < end) { s2 = csr_src[p2]; n2 = csr_norm[p2]; }
            // issue value loads for it+1
            float4 va1 = t4[(size_t)s1 * 16 + l8];
            float4 vb1 = t4[(size_t)s1 * 16 + 8 + l8];
            // compute it
            FMA4(acca, n0, va0)
            FMA4(accb, n0, vb0)
            // rotate
            n0 = n1; va0 = va1; vb0 = vb1;
            s1 = s2; n1 = n2; p1 = p2;
        }
#pragma unroll
        for (int m = 8; m <= 32; m <<= 1) {
            RED4(acca, m)
            RED4(accb, m)
        }
        if (lane < 8) {
            float4 bva = b4[l8], bvb = b4[8 + l8];
            float4 ra, rb;
            ra.x = fmaxf(acca.x + bva.x, 0.f); ra.y = fmaxf(acca.y + bva.y, 0.f);
            ra.z = fmaxf(acca.z + bva.z, 0.f); ra.w = fmaxf(acca.w + bva.w, 0.f);
            rb.x = fmaxf(accb.x + bvb.x, 0.f); rb.y = fmaxf(accb.y + bvb.y, 0.f);
            rb.z = fmaxf(accb.z + bvb.z, 0.f); rb.w = fmaxf(accb.w + bvb.w, 0.f);
            ((float4*)out)[(size_t)node * 16 + l8] = ra;
            ((float4*)out)[(size_t)node * 16 + 8 + l8] = rb;
        }
    }
}

// ---------------- GAT: wat (folded logit weights) + wbig (0.25*gat_w reshaped) ------------
__global__ void k_wat2(const float* __restrict__ gat_w, const float* __restrict__ att_src,
                       const float* __restrict__ att_dst, float* __restrict__ wat,
                       float* __restrict__ wbig) {
    int t = threadIdx.x;  // 512 threads
    int q = t >> 6, cin = t & 63;
    int h = q >> 1;
    const float* av = (q & 1) ? att_dst : att_src;
    float acc = 0.f;
#pragma unroll
    for (int c = 0; c < 64; ++c)
        acc = fmaf(gat_w[cin * 256 + h * 64 + c], av[h * 64 + c], acc);
    wat[t] = acc;
    for (int i = t; i < 256 * 64; i += 512) {
        int k = i >> 6, c = i & 63;
        int hh = k >> 6, ci = k & 63;
        wbig[i] = 0.25f * gat_w[ci * 256 + hh * 64 + c];
    }
}

// asrc/adst = bufA @ wat^T : wave per node (proven kernel, verbatim)
__global__ void k_att2(const float* __restrict__ xin, const float* __restrict__ wat,
                       float* __restrict__ asrc, float* __restrict__ adst) {
    __shared__ float sw[512];
    for (int i = threadIdx.x; i < 512; i += 256) sw[i] = wat[i];
    __syncthreads();
    int node = (blockIdx.x * blockDim.x + threadIdx.x) >> 6;
    int lane = threadIdx.x & 63;
    if (node >= N_NODES) return;
    float val = xin[(size_t)node * 64 + lane];
#pragma unroll
    for (int q = 0; q < 8; ++q) {
        float p = val * sw[q * 64 + lane];
#pragma unroll
        for (int m = 1; m <= 32; m <<= 1) p += __shfl_xor(p, m);
        if (lane == q) {
            if (q & 1) adst[node * 4 + (q >> 1)] = p;
            else       asrc[node * 4 + (q >> 1)] = p;
        }
    }
}

// per (edge,head) unnormalized exp + per (node,head) denominator (proven body, grid-stride)
__global__ __launch_bounds__(256) void k_gat_alpha(
        const int* __restrict__ rowptr, const int* __restrict__ csr_src,
        const float* __restrict__ asrc, const float* __restrict__ adst,
        float* __restrict__ ebuf, float* __restrict__ denom) {
    const int gw = (blockIdx.x * 256 + threadIdx.x) >> 6;
    const int nw = (gridDim.x * 256) >> 6;
    const int lane = threadIdx.x & 63;
    const int h = lane & 3, esub = lane >> 2;  // 16 edges x 4 heads per pass
    for (int node = gw; node < N_NODES; node += nw) {
        int beg = rowptr[node], end = rowptr[node + 1];
        float ad = adst[node * 4 + h];
        float m = -1e30f;
        for (int base = beg; base < end; base += 16) {
            int e = base + esub;
            if (e < end) {
                int s = csr_src[e];
                m = fmaxf(m, lrelu02(asrc[s * 4 + h] + ad));
            }
        }
#pragma unroll
        for (int mk = 4; mk <= 32; mk <<= 1) m = fmaxf(m, __shfl_xor(m, mk));
        float den = 0.f;
        for (int base = beg; base < end; base += 16) {
            int e = base + esub;
            if (e < end) {
                int s = csr_src[e];
                float ex = expf(lrelu02(asrc[s * 4 + h] + ad) - m);
                den += ex;
                ebuf[e * 4 + h] = ex;  // == base*4 + lane : coalesced
            }
        }
#pragma unroll
        for (int mk = 4; mk <= 32; mk <<= 1) den += __shfl_xor(den, mk);
        if (lane < 4) denom[node * 4 + lane] = den;
    }
}

// ---------------- GAT weighted sum v2: 4 edges in flight, 3-stage pipeline --------------
// lane = sub*16 + l16; sub owns edges beg+sub, beg+sub+4, ...; per-lane 4 head accumulators.
// ex read as one float4 per edge (all 4 heads); invalid slots use ex=0.
__global__ __launch_bounds__(256) void k_gat_wsum2(
        const int* __restrict__ rowptr, const int* __restrict__ csr_src,
        const float* __restrict__ ebuf, const float* __restrict__ denom,
        const float* __restrict__ bufA, float* __restrict__ pcat) {
    const int gw = (blockIdx.x * 256 + threadIdx.x) >> 6;
    const int nw = (gridDim.x * 256) >> 6;
    const int lane = threadIdx.x & 63;
    const int sub = lane >> 4, l16 = lane & 15;
    const float4* __restrict__ a4 = (const float4*)bufA;
    const float4* __restrict__ e4 = (const float4*)ebuf;
    const float4 z4 = make_float4(0.f, 0.f, 0.f, 0.f);
    for (int node = gw; node < N_NODES; node += nw) {
        const int beg = rowptr[node], end = rowptr[node + 1];
        const int iters = (end - beg + 3) >> 2;
        float4 acc0 = z4, acc1 = z4, acc2 = z4, acc3 = z4;
        // stage 0: idx+ex for it=0, value load for it=0, idx+ex for it=1
        int p0 = beg + sub;
        int s0 = 0; float4 x0 = z4;
        if (p0 < end) { s0 = csr_src[p0]; x0 = e4[p0]; }
        float4 v0 = a4[(size_t)s0 * 16 + l16];
        int p1 = p0 + 4;
        int s1 = 0; float4 x1 = z4;
        if (p1 < end) { s1 = csr_src[p1]; x1 = e4[p1]; }
        for (int it = 0; it < iters; ++it) {
            // prefetch idx+ex for it+2
            int p2 = p1 + 4;
            int s2 = 0; float4 x2 = z4;
            if (p2 < end) { s2 = csr_src[p2]; x2 = e4[p2]; }
            // issue value load for it+1
            float4 v1 = a4[(size_t)s1 * 16 + l16];
            // compute it
            FMA4(acc0, x0.x, v0)
            FMA4(acc1, x0.y, v0)
            FMA4(acc2, x0.z, v0)
            FMA4(acc3, x0.w, v0)
            // rotate
            x0 = x1; v0 = v1;
            s1 = s2; x1 = x2; p1 = p2;
        }
#pragma unroll
        for (int mk = 16; mk <= 32; mk <<= 1) {
            RED4(acc0, mk)
            RED4(acc1, mk)
            RED4(acc2, mk)
            RED4(acc3, mk)
        }
        float4 dn = ((const float4*)denom)[node];
        if (lane < 16) {
            float i0 = 1.0f / dn.x, i1 = 1.0f / dn.y;
            float i2 = 1.0f / dn.z, i3 = 1.0f / dn.w;
            acc0.x *= i0; acc0.y *= i0; acc0.z *= i0; acc0.w *= i0;
            acc1.x *= i1; acc1.y *= i1; acc1.z *= i1; acc1.w *= i1;
            acc2.x *= i2; acc2.y *= i2; acc2.z *= i2; acc2.w *= i2;
            acc3.x *= i3; acc3.y *= i3; acc3.z *= i3; acc3.w *= i3;
            float4* pr = (float4*)(pcat + (size_t)node * 256);
            pr[l16]      = acc0;
            pr[16 + l16] = acc1;
            pr[32 + l16] = acc2;
            pr[48 + l16] = acc3;
        }
    }
}

// ---------------- pool (batch sorted: run-length accumulate, 32 nodes/wave) ----------------
__global__ void k_pool2(const int* __restrict__ batch, const float* __restrict__ h,
                        float* __restrict__ psum, float* __restrict__ pcnt) {
    int wave = (blockIdx.x * blockDim.x + threadIdx.x) >> 6;
    int lane = threadIdx.x & 63;
    int n0 = wave * 32;
    if (n0 >= N_NODES) return;
    int nend = min(n0 + 32, N_NODES);
    int cur = batch[n0];
    float acc = 0.f, cnt = 0.f;
    for (int n = n0; n < nend; ++n) {
        int g = batch[n];
        if (g != cur) {
            atomicAdd(&psum[cur * 64 + lane], acc);
            if (lane == 0) atomicAdd(&pcnt[cur], cnt);
            acc = 0.f; cnt = 0.f; cur = g;
        }
        acc += h[(size_t)n * 64 + lane];
        cnt += 1.f;
    }
    atomicAdd(&psum[cur * 64 + lane], acc);
    if (lane == 0) atomicAdd(&pcnt[cur], cnt);
}

__global__ void k_cls(const float* __restrict__ psum, const float* __restrict__ pcnt,
                      const float* __restrict__ cw1, const float* __restrict__ cb1,
                      const float* __restrict__ cw2, const float* __restrict__ cb2,
                      float* __restrict__ out) {
    int g = blockIdx.x;
    int j = threadIdx.x;
    __shared__ float sp[64];
    float rc = 1.0f / fmaxf(pcnt[g], 1.0f);
    sp[j] = psum[g * 64 + j] * rc;
    __syncthreads();
    float z = 0.f;
    if (j < 32) {
        float acc = 0.f;
#pragma unroll
        for (int k = 0; k < 64; ++k) acc = fmaf(sp[k], cw1[k * 32 + j], acc);
        acc += cb1[j];
        acc = fmaxf(acc, 0.f);
        z = acc * cw2[j];
    }
#pragma unroll
    for (int off = 32; off; off >>= 1) z += __shfl_down(z, off);
    if (j == 0) out[g] = z + cb2[0];
}

extern "C" void kernel_launch(void* const* d_in, const int* in_sizes, int n_in,
                              void* d_out, int out_size, void* d_ws, size_t ws_size,
                              hipStream_t stream) {
    const float* x       = (const float*)d_in[0];
    const int*   ei      = (const int*)d_in[1];
    const int*   batch   = (const int*)d_in[2];
    const float* w1      = (const float*)d_in[3];
    const float* b1      = (const float*)d_in[4];
    const float* w2      = (const float*)d_in[5];
    const float* b2      = (const float*)d_in[6];
    const float* w3      = (const float*)d_in[7];
    const float* b3      = (const float*)d_in[8];
    const float* gat_w   = (const float*)d_in[9];
    const float* att_src = (const float*)d_in[10];
    const float* att_dst = (const float*)d_in[11];
    const float* gat_b   = (const float*)d_in[12];
    const float* cw1     = (const float*)d_in[13];
    const float* cb1     = (const float*)d_in[14];
    const float* cw2     = (const float*)d_in[15];
    const float* cb2     = (const float*)d_in[16];
    float* out = (float*)d_out;

    const int* srcp = ei;
    const int* dstp = ei + N_EDGES;

    // workspace (all chunks multiple-of-4 floats for float4 alignment)
    float* W = (float*)d_ws;
    size_t off = 0;
    float*    dinv    = W + off; off += N_NODES;
    int*      rowptr  = (int*)(W + off); off += N_NODES + 4;
    int*      partial = (int*)(W + off); off += 256;
    int*      cursor  = (int*)(W + off); off += N_NODES;
    int*      csr_src = (int*)(W + off); off += E_TOT;
    float*    csr_nrm = W + off; off += E_TOT;
    float*    bufT    = W + off; off += (size_t)N_NODES * HID;
    float*    bufA    = W + off; off += (size_t)N_NODES * HID;
    float*    bufB    = W + off; off += (size_t)N_NODES * HID;
    float*    pcat    = W + off; off += (size_t)N_NODES * 256;
    float*    asrc    = W + off; off += (size_t)N_NODES * 4;
    float*    adst    = W + off; off += (size_t)N_NODES * 4;
    float*    ebuf    = W + off; off += (size_t)E_TOT * 4;
    float*    denom   = W + off; off += (size_t)N_NODES * 4;
    float*    wat     = W + off; off += 512;
    float*    wbig    = W + off; off += 256 * 64;
    // contiguous zero-init region: degi + psum + pcnt
    int*      degi    = (int*)(W + off); off += N_NODES;
    float*    psum    = W + off; off += (size_t)N_GRAPHS * HID;
    float*    pcnt    = W + off; off += N_GRAPHS;

    auto cdiv = [](int a, int b) { return (a + b - 1) / b; };

    hipMemsetAsync(degi, 0, (N_NODES + N_GRAPHS * HID + N_GRAPHS) * sizeof(int), stream);

    // degree / CSR (dinv fused into scan1, self-loop fill into scan3)
    k_deg<<<cdiv(N_EDGES, 256), 256, 0, stream>>>(dstp, degi);
    k_scan1<<<SCAN_NB, 256, 0, stream>>>(degi, rowptr, partial, dinv);
    k_scan2<<<1, 256, 0, stream>>>(partial);
    k_scan3<<<SCAN_NB, 256, 0, stream>>>(rowptr, partial, dinv, csr_src, csr_nrm, cursor);
    k_fill_edge<<<cdiv(N_EDGES, 256), 256, 0, stream>>>(srcp, dstp, rowptr, dinv, cursor,
                                                        csr_src, csr_nrm);
    k_wat2<<<1, 512, 0, stream>>>(gat_w, att_src, att_dst, wat, wbig);

    const int nGS = 2048;                  // grid-stride blocks
    const int nWV = cdiv(N_NODES * 64, 256);
    const int nGB = cdiv(N_NODES, 64);     // gemm blocks

    // GCN layer 1 (K=128): x -> bufA
    k_gemm_v3<F_IN, false><<<nGB, 256, 0, stream>>>(x, w1, nullptr, bufT, N_NODES);
    k_gcn_gather_v4<<<nGS, 256, 0, stream>>>(rowptr, csr_src, csr_nrm, bufT, b1, bufA);
    // GCN layer 2: bufA -> bufB
    k_gemm_v3<HID, false><<<nGB, 256, 0, stream>>>(bufA, w2, nullptr, bufT, N_NODES);
    k_gcn_gather_v4<<<nGS, 256, 0, stream>>>(rowptr, csr_src, csr_nrm, bufT, b2, bufB);
    // GCN layer 3: bufB -> bufA
    k_gemm_v3<HID, false><<<nGB, 256, 0, stream>>>(bufB, w3, nullptr, bufT, N_NODES);
    k_gcn_gather_v4<<<nGS, 256, 0, stream>>>(rowptr, csr_src, csr_nrm, bufT, b3, bufA);

    // GAT: att2 -> alpha -> wsum2, then [N,256]@[256,64] GEMM (+bias+relu)
    k_att2<<<nWV, 256, 0, stream>>>(bufA, wat, asrc, adst);
    k_gat_alpha<<<nGS, 256, 0, stream>>>(rowptr, csr_src, asrc, adst, ebuf, denom);
    k_gat_wsum2<<<nGS, 256, 0, stream>>>(rowptr, csr_src, ebuf, denom, bufA, pcat);
    k_gemm_v3<256, true><<<nGB, 256, 0, stream>>>(pcat, wbig, gat_b, bufB, N_NODES);

    // pool + classifier
    k_pool2<<<cdiv(cdiv(N_NODES, 32) * 64, 256), 256, 0, stream>>>(batch, bufB, psum, pcnt);
    k_cls<<<N_GRAPHS, 64, 0, stream>>>(psum, pcnt, cw1, cb1, cw2, cb2, out);
}